// Round 5
// baseline (233.798 us; speedup 1.0000x reference)
//
#include <hip/hip_runtime.h>

#define IMG   256
#define IMG2  65536
#define NB    64
#define NB2   128

// ---------------------------------------------------------------------------
// R5: per-wave burst coarsening. Evidence: harness fill kernel sustains
// 6.8 TB/s writes at 10% occupancy with long independent store bursts; our
// waves did 2 loads -> dependent shuffle chain -> 2 stores at 2.9 TB/s.
// Coarser waves: 8 loads in flight, independent reduce chains, 8-store
// bursts; label waves process 2 rows (18 loads in flight).
// __launch_bounds__(256,4): cap VGPR at 128, guarantee 16 waves/CU.
//   crops_kernel: 2560 blocks (s8: 512, s16: 1024, s32: 1024)
//   label_kernel: 2048 blocks (wave = 2 rows)
// ---------------------------------------------------------------------------

__device__ __forceinline__ float4 norm4(float4 a, float mn, float inv) {
    float4 o;
    o.x = (a.x - mn) * inv; o.y = (a.y - mn) * inv;
    o.z = (a.z - mn) * inv; o.w = (a.w - mn) * inv;
    return o;
}

__device__ __forceinline__ void mm4(float4 a, float& mn, float& mx) {
    mn = fminf(mn, fminf(fminf(a.x, a.y), fminf(a.z, a.w)));
    mx = fmaxf(mx, fmaxf(fmaxf(a.x, a.y), fmaxf(a.z, a.w)));
}

// S=8: wave = one full cell-row (8 rows x 256 cols = 32 cells) of one src.
// Processed as 2 half-batches of 4 strips (strip = 8x32 = 4 cells).
// lane = r*8 + cell*2 + half within a strip; cell-mates differ in bits
// {0,3,4,5} -> shfl_xor offsets {1,8,16,32}.
// Heat row (32 A + 32 B values) loaded once, distributed via __shfl.
__device__ __forceinline__ void crops_s8(
    const float* __restrict__ img, const float* __restrict__ heat,
    float* __restrict__ out, int wid) {
    const int l   = threadIdx.x & 63;
    const int src = wid >> 5;        // 0..63
    const int ci  = wid & 31;

    const int r   = l >> 3;
    const int c8  = l & 7;
    const int sub = (l >> 1) & 3;
    const int o   = (l & 1) * 4;
    const int rowA = ci * 8 + r;
    const int rowB = ((ci == 0) ? 0 : ci * 8 - 4) + r;

    const float* __restrict__ sp  = img + (size_t)src * IMG2;
    const float* __restrict__ rpA = sp + rowA * IMG;
    const float* __restrict__ rpB = sp + rowB * IMG;
    float* __restrict__ dA = out + (size_t)src * IMG2 + rowA * IMG;
    float* __restrict__ dB = dA + (size_t)NB * IMG2;

    // lane<32 holds heatA[cell l], lane>=32 holds heatB[cell l-32]
    const float hpack =
        heat[(size_t)(src + ((l >= 32) ? NB : 0)) * 1024 + ci * 32 + (l & 31)];

#pragma unroll
    for (int h = 0; h < 2; ++h) {
        float4 a[4], bq[4];
#pragma unroll
        for (int k = 0; k < 4; ++k) {
            const int st   = h * 4 + k;
            const int cj   = st * 4 + sub;
            const int colA = st * 32 + c8 * 4;
            const int colB = ((cj == 0) ? 0 : cj * 8 - 4) + o;
            a[k]  = *(const float4*)(rpA + colA);
            bq[k] = *(const float4*)(rpB + colB);
        }
#pragma unroll
        for (int k = 0; k < 4; ++k) {
            const int st = h * 4 + k;
            const int cj = st * 4 + sub;
            float mnA = 3.4e38f, mxA = -3.4e38f, mnB = 3.4e38f, mxB = -3.4e38f;
            mm4(a[k], mnA, mxA); mm4(bq[k], mnB, mxB);
#pragma unroll
            for (int s = 0; s < 4; ++s) {
                const int off = (s == 0) ? 1 : (4 << s);  // 1, 8, 16, 32
                mnA = fminf(mnA, __shfl_xor(mnA, off, 64));
                mxA = fmaxf(mxA, __shfl_xor(mxA, off, 64));
                mnB = fminf(mnB, __shfl_xor(mnB, off, 64));
                mxB = fmaxf(mxB, __shfl_xor(mxB, off, 64));
            }
            const float hA = __shfl(hpack, cj, 64);
            const float hB = __shfl(hpack, 32 + cj, 64);
            const float invA = (hA > 0.5f ? 1.0f : 0.0f) / (mxA - mnA + 1e-5f);
            const float invB = (hB > 0.5f ? 1.0f : 0.0f) / (mxB - mnB + 1e-5f);
            const int colA = st * 32 + c8 * 4;
            *(float4*)(dA + colA) = norm4(a[k],  mnA, invA);
            *(float4*)(dB + colA) = norm4(bq[k], mnB, invB);
        }
    }
}

// S=16: wave = 4 cells (one quarter of a cell-row); lane = r*4 + quarter.
__device__ __forceinline__ void crops_s16(
    const float* __restrict__ img, const float* __restrict__ heat,
    float* __restrict__ out, int wid) {
    const int l   = threadIdx.x & 63;
    const int src = wid >> 6;        // 0..63
    const int rem = wid & 63;
    const int ci  = rem >> 2;
    const int q   = rem & 3;

    const int r    = l >> 2;
    const int o    = (l & 3) * 4;
    const int rowA = ci * 16 + r;
    const int rowB = ((ci == 0) ? 0 : ci * 16 - 4) + r;

    const float* __restrict__ sp  = img + (size_t)src * IMG2;
    const float* __restrict__ rpA = sp + rowA * IMG;
    const float* __restrict__ rpB = sp + rowB * IMG;
    float* __restrict__ dA = out + (size_t)src * IMG2 + rowA * IMG;
    float* __restrict__ dB = dA + (size_t)NB * IMG2;

    float4 a[4], bq[4];
#pragma unroll
    for (int k = 0; k < 4; ++k) {
        const int cj   = q * 4 + k;
        const int colA = cj * 16 + o;
        const int colB = ((cj == 0) ? 0 : cj * 16 - 4) + o;
        a[k]  = *(const float4*)(rpA + colA);
        bq[k] = *(const float4*)(rpB + colB);
    }
#pragma unroll
    for (int k = 0; k < 4; ++k) {
        const int cj = q * 4 + k;
        float mnA = 3.4e38f, mxA = -3.4e38f, mnB = 3.4e38f, mxB = -3.4e38f;
        mm4(a[k], mnA, mxA); mm4(bq[k], mnB, mxB);
#pragma unroll
        for (int off = 1; off < 64; off <<= 1) {
            mnA = fminf(mnA, __shfl_xor(mnA, off, 64));
            mxA = fmaxf(mxA, __shfl_xor(mxA, off, 64));
            mnB = fminf(mnB, __shfl_xor(mnB, off, 64));
            mxB = fmaxf(mxB, __shfl_xor(mxB, off, 64));
        }
        const float hA = heat[(size_t)src * 256 + ci * 16 + cj];
        const float hB = heat[(size_t)(src + NB) * 256 + ci * 16 + cj];
        const float invA = (hA > 0.5f ? 1.0f : 0.0f) / (mxA - mnA + 1e-5f);
        const float invB = (hB > 0.5f ? 1.0f : 0.0f) / (mxB - mnB + 1e-5f);
        const int colA = cj * 16 + o;
        *(float4*)(dA + colA) = norm4(a[k],  mnA, invA);
        *(float4*)(dB + colA) = norm4(bq[k], mnB, invB);
    }
}

// S=32: wave = one 32x32 cell, 4 row-iterations held in registers.
__device__ __forceinline__ void crops_s32(
    const float* __restrict__ img, const float* __restrict__ heat,
    float* __restrict__ out, int wid) {
    const int l   = threadIdx.x & 63;
    const int src = wid >> 6;
    const int rem = wid & 63;
    const int ci  = rem >> 3;
    const int cj  = rem & 7;

    const int r0   = l >> 3;
    const int o    = (l & 7) * 4;
    const int rA   = ci * 32;
    const int rB   = (ci == 0) ? 0 : rA - 4;
    const int colA = cj * 32 + o;
    const int colB = ((cj == 0) ? 0 : cj * 32 - 4) + o;

    const float* __restrict__ sp = img + (size_t)src * IMG2;
    float4 a[4], bq[4];
#pragma unroll
    for (int k = 0; k < 4; ++k) {
        const int r = r0 + 8 * k;
        a[k]  = *(const float4*)(sp + (rA + r) * IMG + colA);
        bq[k] = *(const float4*)(sp + (rB + r) * IMG + colB);
    }
    float mnA = 3.4e38f, mxA = -3.4e38f, mnB = 3.4e38f, mxB = -3.4e38f;
#pragma unroll
    for (int k = 0; k < 4; ++k) { mm4(a[k], mnA, mxA); mm4(bq[k], mnB, mxB); }
#pragma unroll
    for (int off = 1; off < 64; off <<= 1) {
        mnA = fminf(mnA, __shfl_xor(mnA, off, 64));
        mxA = fmaxf(mxA, __shfl_xor(mxA, off, 64));
        mnB = fminf(mnB, __shfl_xor(mnB, off, 64));
        mxB = fmaxf(mxB, __shfl_xor(mxB, off, 64));
    }
    const float hA = heat[(size_t)src * 64 + ci * 8 + cj];
    const float hB = heat[(size_t)(src + NB) * 64 + ci * 8 + cj];
    const float invA = (hA > 0.5f ? 1.0f : 0.0f) / (mxA - mnA + 1e-5f);
    const float invB = (hB > 0.5f ? 1.0f : 0.0f) / (mxB - mnB + 1e-5f);

    float* __restrict__ dA = out + (size_t)src * IMG2;
    float* __restrict__ dB = out + (size_t)(src + NB) * IMG2;
#pragma unroll
    for (int k = 0; k < 4; ++k) {
        const int r = r0 + 8 * k;
        *(float4*)(dA + (rA + r) * IMG + colA) = norm4(a[k],  mnA, invA);
        *(float4*)(dB + (rA + r) * IMG + colA) = norm4(bq[k], mnB, invB);
    }
}

// ---------------------------------------------------------------------------
// label: generic (edge) single-row path — full 2x2 preimage with masks.
// ---------------------------------------------------------------------------
__device__ __forceinline__ void label_row_generic(
    const float* __restrict__ heat8,
    const float* __restrict__ heat16,
    const float* __restrict__ heat32,
    const float* __restrict__ seg8,
    const float* __restrict__ seg16,
    const float* __restrict__ seg32,
    float* __restrict__ out,
    int b, int u, int v0, int vs) {
    float nu[4] = {0.f, 0.f, 0.f, 0.f};
    float de[4] = {0.f, 0.f, 0.f, 0.f};
    const int i0  = u;
    const int i1c = min(u + 4, 255);
#define SCALE_G(heat, seg, g, l, s)                                           \
    {                                                                         \
        const float* __restrict__ h1 = heat + b * (g * g);                    \
        const float* __restrict__ h2 = heat + (NB + b) * (g * g);             \
        const float* __restrict__ r1 = seg + (size_t)b * IMG2 + u * IMG;      \
        const float* __restrict__ ra =                                        \
            seg + (size_t)(NB + b) * IMG2 + i0 * IMG;                         \
        const float* __restrict__ rb =                                        \
            seg + (size_t)(NB + b) * IMG2 + i1c * IMG;                        \
        const float4 sd  = *(const float4*)(r1 + v0);                         \
        const float4 a0q = *(const float4*)(ra + v0);                         \
        const float4 a1q = *(const float4*)(ra + vs);                         \
        const float4 b0q = *(const float4*)(rb + v0);                         \
        const float4 b1q = *(const float4*)(rb + vs);                         \
        const float hd  = h1[(u >> l) * g + (v0 >> l)];                       \
        const float hA0 = h2[(i0 >> l) * g + (v0 >> l)];                      \
        const float hA1 = h2[(i0 >> l) * g + (vs >> l)];                      \
        const float hB0 = h2[(i1c >> l) * g + (v0 >> l)];                     \
        const float hB1 = h2[(i1c >> l) * g + (vs >> l)];                     \
        const float miA = (u < (s)) ? 1.0f : 0.0f;                            \
        const float miB = (u >= (s) - 4 && u <= 251) ? 1.0f : 0.0f;           \
        const float md  = (hd > 0.5f) ? 1.0f : 0.0f;                          \
        const float gA0 = miA * ((hA0 > 0.5f) ? 1.0f : 0.0f);                 \
        const float gA1 = miA * ((hA1 > 0.5f) ? 1.0f : 0.0f);                 \
        const float gB0 = miB * ((hB0 > 0.5f) ? 1.0f : 0.0f);                 \
        const float gB1 = miB * ((hB1 > 0.5f) ? 1.0f : 0.0f);                 \
        _Pragma("unroll")                                                     \
        for (int c = 0; c < 4; ++c) {                                         \
            const int v = v0 + c;                                             \
            const float mj0 = (v < (s)) ? 1.0f : 0.0f;                        \
            const float mj1 = (v >= (s) - 4 && v <= 251) ? 1.0f : 0.0f;       \
            const float w00 = gA0 * mj0, w01 = gA1 * mj1;                     \
            const float w10 = gB0 * mj0, w11 = gB1 * mj1;                     \
            float x = ((const float*)&sd)[c] * md;                            \
            x = fmaf(w00, ((const float*)&a0q)[c], x);                        \
            x = fmaf(w01, ((const float*)&a1q)[c], x);                        \
            x = fmaf(w10, ((const float*)&b0q)[c], x);                        \
            x = fmaf(w11, ((const float*)&b1q)[c], x);                        \
            nu[c] += x;                                                       \
            de[c] += md + w00 + w01 + w10 + w11;                              \
        }                                                                     \
    }
    SCALE_G(heat32, seg32, 32, 3, 8)
    SCALE_G(heat16, seg16, 16, 4, 16)
    SCALE_G(heat8,  seg8,  8,  5, 32)
#undef SCALE_G
    float4 o;
    o.x = nu[0] / (de[0] + 1e-10f);
    o.y = nu[1] / (de[1] + 1e-10f);
    o.z = nu[2] / (de[2] + 1e-10f);
    o.w = nu[3] / (de[3] + 1e-10f);
    *(float4*)(out + (size_t)b * IMG2 + u * IMG + v0) = o;
}

// ---------------------------------------------------------------------------
// label kernel: one wave per ROW PAIR (u, u+1). Fast path (u in [32,250]):
// only preimage row i = u+4 exists -> 18 float4 loads in flight per wave.
// ---------------------------------------------------------------------------
__global__ __launch_bounds__(256, 4) void label_kernel(
    const float* __restrict__ heat8,
    const float* __restrict__ heat16,
    const float* __restrict__ heat32,
    const float* __restrict__ seg8,
    const float* __restrict__ seg16,
    const float* __restrict__ seg32,
    float* __restrict__ out) {
    float* label = out + (size_t)3 * NB2 * IMG2;    // (64,1,256,256)
    const int lid  = blockIdx.x * 4 + (threadIdx.x >> 6);  // 0..8191
    const int b    = lid >> 7;
    const int u    = (lid & 127) << 1;
    const int lane = threadIdx.x & 63;
    const int v0   = lane << 2;
    const int vs   = min(v0 + 4, 252);

    if (u >= 32 && u <= 250) {
        float nu0[4] = {0.f,0.f,0.f,0.f}, de0[4] = {0.f,0.f,0.f,0.f};
        float nu1[4] = {0.f,0.f,0.f,0.f}, de1[4] = {0.f,0.f,0.f,0.f};
#define SCALE_F2(heat, seg, g, l, s)                                          \
        {                                                                     \
            const float* __restrict__ h1 = heat + b * (g * g);                \
            const float* __restrict__ h2 = heat + (NB + b) * (g * g);         \
            const float* __restrict__ r1 = seg + (size_t)b * IMG2 + u * IMG;  \
            const float* __restrict__ r2 =                                    \
                seg + (size_t)(NB + b) * IMG2 + (u + 4) * IMG;                \
            const float4 sd0 = *(const float4*)(r1 + v0);                     \
            const float4 sd1 = *(const float4*)(r1 + IMG + v0);               \
            const float4 g00 = *(const float4*)(r2 + v0);                     \
            const float4 g10 = *(const float4*)(r2 + vs);                     \
            const float4 g01 = *(const float4*)(r2 + IMG + v0);               \
            const float4 g11 = *(const float4*)(r2 + IMG + vs);               \
            const float hd0  = h1[(u >> l) * g + (v0 >> l)];                  \
            const float hd1  = h1[((u + 1) >> l) * g + (v0 >> l)];            \
            const float hg00 = h2[((u + 4) >> l) * g + (v0 >> l)];            \
            const float hg10 = h2[((u + 4) >> l) * g + (vs >> l)];            \
            const float hg01 = h2[((u + 5) >> l) * g + (v0 >> l)];            \
            const float hg11 = h2[((u + 5) >> l) * g + (vs >> l)];            \
            const float md0 = (hd0 > 0.5f) ? 1.0f : 0.0f;                     \
            const float md1 = (hd1 > 0.5f) ? 1.0f : 0.0f;                     \
            const float q00 = (hg00 > 0.5f) ? 1.0f : 0.0f;                    \
            const float q10 = (hg10 > 0.5f) ? 1.0f : 0.0f;                    \
            const float q01 = (hg01 > 0.5f) ? 1.0f : 0.0f;                    \
            const float q11 = (hg11 > 0.5f) ? 1.0f : 0.0f;                    \
            _Pragma("unroll")                                                 \
            for (int c = 0; c < 4; ++c) {                                     \
                const int v = v0 + c;                                         \
                const float mj0 = (v < (s)) ? 1.0f : 0.0f;                    \
                const float mj1 = (v >= (s) - 4 && v <= 251) ? 1.0f : 0.0f;   \
                const float m00 = mj0 * q00, m10 = mj1 * q10;                 \
                const float m01 = mj0 * q01, m11 = mj1 * q11;                 \
                float x0 = ((const float*)&sd0)[c] * md0;                     \
                x0 = fmaf(m00, ((const float*)&g00)[c], x0);                  \
                x0 = fmaf(m10, ((const float*)&g10)[c], x0);                  \
                nu0[c] += x0;                                                 \
                de0[c] += md0 + m00 + m10;                                    \
                float x1 = ((const float*)&sd1)[c] * md1;                     \
                x1 = fmaf(m01, ((const float*)&g01)[c], x1);                  \
                x1 = fmaf(m11, ((const float*)&g11)[c], x1);                  \
                nu1[c] += x1;                                                 \
                de1[c] += md1 + m01 + m11;                                    \
            }                                                                 \
        }
        SCALE_F2(heat32, seg32, 32, 3, 8)
        SCALE_F2(heat16, seg16, 16, 4, 16)
        SCALE_F2(heat8,  seg8,  8,  5, 32)
#undef SCALE_F2
        float4 o0, o1;
        o0.x = nu0[0] / (de0[0] + 1e-10f);
        o0.y = nu0[1] / (de0[1] + 1e-10f);
        o0.z = nu0[2] / (de0[2] + 1e-10f);
        o0.w = nu0[3] / (de0[3] + 1e-10f);
        o1.x = nu1[0] / (de1[0] + 1e-10f);
        o1.y = nu1[1] / (de1[1] + 1e-10f);
        o1.z = nu1[2] / (de1[2] + 1e-10f);
        o1.w = nu1[3] / (de1[3] + 1e-10f);
        float* p = label + (size_t)b * IMG2 + u * IMG + v0;
        *(float4*)p         = o0;
        *(float4*)(p + IMG) = o1;
    } else {
        label_row_generic(heat8, heat16, heat32, seg8, seg16, seg32, label,
                          b, u,     v0, vs);
        label_row_generic(heat8, heat16, heat32, seg8, seg16, seg32, label,
                          b, u + 1, v0, vs);
    }
}

__global__ __launch_bounds__(256, 4) void crops_kernel(
    const float* __restrict__ img,
    const float* __restrict__ heat8,
    const float* __restrict__ heat16,
    const float* __restrict__ heat32,
    float* __restrict__ out) {
    float* crops32 = out;                           // (128,1,256,256) s=8
    float* crops16 = out + (size_t)NB2 * IMG2;      // s=16
    float* crops8  = out + (size_t)2 * NB2 * IMG2;  // s=32

    const int cb = blockIdx.x;                      // 0 .. 2559
    const int w  = threadIdx.x >> 6;
    if (cb < 512) {
        crops_s8(img, heat32, crops32, cb * 4 + w);          // wid 0..2047
    } else if (cb < 1536) {
        crops_s16(img, heat16, crops16, (cb - 512) * 4 + w); // wid 0..4095
    } else {
        crops_s32(img, heat8, crops8, (cb - 1536) * 4 + w);  // wid 0..4095
    }
}

extern "C" void kernel_launch(void* const* d_in, const int* in_sizes, int n_in,
                              void* d_out, int out_size, void* d_ws, size_t ws_size,
                              hipStream_t stream) {
    const float* img    = (const float*)d_in[0];
    const float* heat8  = (const float*)d_in[1];
    const float* heat16 = (const float*)d_in[2];
    const float* heat32 = (const float*)d_in[3];
    const float* seg8   = (const float*)d_in[4];
    const float* seg16  = (const float*)d_in[5];
    const float* seg32  = (const float*)d_in[6];

    label_kernel<<<dim3(2048), 256, 0, stream>>>(
        heat8, heat16, heat32, seg8, seg16, seg32, (float*)d_out);
    crops_kernel<<<dim3(2560), 256, 0, stream>>>(
        img, heat8, heat16, heat32, (float*)d_out);
}